// Round 10
// baseline (52.343 us; speedup 1.0000x reference)
//
#include <hip/hip_runtime.h>

// ExplicitLiePE via MFMA: y[b,s] = expm(A) @ x[b,s], A = sum_k r_k * 0.5*(L_k - L_k^T).
//
// Ladder: r5 1-wave/16tok +LDS exchange = 42us (latency-bound). r6 row-split
// 4-wave = 32us (barrier chain ~1400cy/step, 2 waves/SIMD). r7-r9: occupancy
// via duplication/fatter blocks all regressed -- token axis can't feed both.
//
// Round-10: DELETE the exchange. The A/B k-slot bijection sigma is a free
// choice (any permutation applied to BOTH operands leaves the contraction
// invariant -- validated r5-r9). Choose
//     sigma(g, j, kt) = 32*kt + 4*g + (j&3) + 16*(j>>2)
// Then B-fragment element (lane (c,g), slot j, tile kt) = b[token c][row
// 32kt + 16(j>>2) + 4g + (j&3)] = this lane's OWN accumulator b1[8kt + j]
// (D-layout rows of lane (c,g) are 16*m2 + 4*g + r, i = 4*m2+r).
// The D->B exchange becomes an in-register cvt_pk: Bh[kt] = pack(b1[8kt..+7]).
// The prepass absorbs sigma into the A-fragment gather.
//
// One wave owns 16 tokens fully: 72 MFMAs/step (4 m2-tiles x 3 gen x {hh,hl,lh}),
// ZERO LDS / barriers / cross-lane ops in the main loop. Step critical path
// drops ~1400cy -> ~200cy; the wave becomes issue-bound (~800cy/step).
// 512 independent 1-wave workgroups; idle SIMDs don't matter when issue-bound.
//
// Math (unchanged): Clenshaw on Chebyshev/Bessel expansion of exp(A)x with
// on-the-fly Miller recurrence; f16 hi/lo split of both L' and b
// (Lhi.bhi + Lhi.blo + Llo.bhi; dropped term ~2^-24); per-step renorm
// s = jc>1 ? rcp(jc) : 1 (result scale-invariant). Seed at m==ms, coeff
// gated by m<=M. Per-token sequence identical to r6 (MFMA-internal k-order
// permutes -> ulp-level drift only; absmax ~0.0156).
//
// Layouts:
//  - C/D (HW-verified m89/m91): reg r of lane l, tile m2 = D[16m2+(l>>4)*4+r][l&15].
//  - A prepass element (l, j) of tile (gen,m2,kt) =
//      L'[16*m2 + (l&15)][32*kt + 4*(l>>4) + (j&3) + 16*(j>>2)].

typedef _Float16 half8 __attribute__((ext_vector_type(8)));
typedef __fp16 fp16x2 __attribute__((ext_vector_type(2)));
typedef float float4t __attribute__((ext_vector_type(4)));

union H2U { fp16x2 h; unsigned u; };
union H8U { half8 h; uint4 u; };

__device__ __forceinline__ unsigned pkrtz2(float a, float b) {
    H2U v; v.h = __builtin_amdgcn_cvt_pkrtz(a, b); return v.u;
}
__device__ __forceinline__ float h2lo(unsigned u) { H2U v; v.u = u; return (float)v.h[0]; }
__device__ __forceinline__ float h2hi(unsigned u) { H2U v; v.u = u; return (float)v.h[1]; }

// ---------------- prepass: skew-symmetrize + f16 hi/lo split into fragments ----
// ws layout (f16): hi at [f*512 + l*8 + j], lo at +12288, f = gen*8 + m2*2 + kt.
__global__ void liepe_prep(const float* __restrict__ L, _Float16* __restrict__ wsA)
{
    int t = blockIdx.x * 256 + threadIdx.x;
    if (t >= 1536) return;
    int l   = t & 63;
    int f   = t >> 6;
    int kt  = f & 1;
    int m2  = (f >> 1) & 3;
    int gen = f >> 3;
    int i   = 16 * m2 + (l & 15);
    int g   = l >> 4;
    const float* Lg = L + gen * 4096;
    half8 hi, lo;
    #pragma unroll
    for (int j = 0; j < 8; ++j) {
        int kk = 32 * kt + 4 * g + (j & 3) + 16 * (j >> 2);   // sigma(g,j,kt)
        float d = Lg[i * 64 + kk] - Lg[kk * 64 + i];
        _Float16 h = (_Float16)d;
        hi[j] = h;
        lo[j] = (_Float16)(d - (float)h);
    }
    *(half8*)(wsA + f * 512 + l * 8) = hi;
    *(half8*)(wsA + 12288 + f * 512 + l * 8) = lo;
}

// ---------------- main kernel: 1 wave per 16 tokens, register-only loop ------

// Pack b1 (16 f32, D-layout) -> B fragments, hi/lo. Slot j of tile kt = b1[8kt+j].
#define PACK_B()                                                              \
  {                                                                           \
    _Pragma("unroll")                                                         \
    for (int kt = 0; kt < 2; ++kt) {                                          \
      H8U bh, bl;                                                             \
      bh.u.x = pkrtz2(b1[8*kt+0], b1[8*kt+1]);                                \
      bh.u.y = pkrtz2(b1[8*kt+2], b1[8*kt+3]);                                \
      bh.u.z = pkrtz2(b1[8*kt+4], b1[8*kt+5]);                                \
      bh.u.w = pkrtz2(b1[8*kt+6], b1[8*kt+7]);                                \
      bl.u.x = pkrtz2(b1[8*kt+0]-h2lo(bh.u.x), b1[8*kt+1]-h2hi(bh.u.x));      \
      bl.u.y = pkrtz2(b1[8*kt+2]-h2lo(bh.u.y), b1[8*kt+3]-h2hi(bh.u.y));      \
      bl.u.z = pkrtz2(b1[8*kt+4]-h2lo(bh.u.z), b1[8*kt+5]-h2hi(bh.u.z));      \
      bl.u.w = pkrtz2(b1[8*kt+6]-h2lo(bh.u.w), b1[8*kt+7]-h2hi(bh.u.w));      \
      Bh[kt] = bh.h; Bl[kt] = bl.h;                                           \
    }                                                                         \
  }

// 72 MFMAs: 4 m2-tiles x 3 gen x (AhBh + AhBl + AlBh), kt-split acc chains.
#define GEMM_COMBINE(TOUT)                                                    \
  {                                                                           \
    _Pragma("unroll")                                                         \
    for (int m2 = 0; m2 < 4; ++m2) {                                          \
      _Pragma("unroll")                                                       \
      for (int gen = 0; gen < 3; ++gen) {                                     \
        float q = (gen == 0) ? q0 : ((gen == 1) ? q1 : q2);                   \
        const int f0 = gen * 8 + m2 * 2;                                      \
        float4t ac0 = {0.f, 0.f, 0.f, 0.f};                                   \
        float4t ac1 = {0.f, 0.f, 0.f, 0.f};                                   \
        ac0 = __builtin_amdgcn_mfma_f32_16x16x32_f16(Ah[f0+0], Bh[0], ac0, 0, 0, 0); \
        ac1 = __builtin_amdgcn_mfma_f32_16x16x32_f16(Ah[f0+1], Bh[1], ac1, 0, 0, 0); \
        ac0 = __builtin_amdgcn_mfma_f32_16x16x32_f16(Ah[f0+0], Bl[0], ac0, 0, 0, 0); \
        ac1 = __builtin_amdgcn_mfma_f32_16x16x32_f16(Ah[f0+1], Bl[1], ac1, 0, 0, 0); \
        ac0 = __builtin_amdgcn_mfma_f32_16x16x32_f16(Al[f0+0], Bh[0], ac0, 0, 0, 0); \
        ac1 = __builtin_amdgcn_mfma_f32_16x16x32_f16(Al[f0+1], Bh[1], ac1, 0, 0, 0); \
        _Pragma("unroll")                                                     \
        for (int r4 = 0; r4 < 4; ++r4) {                                      \
          float sum = ac0[r4] + ac1[r4];                                      \
          if (gen == 0) TOUT[m2 * 4 + r4] = q * sum;                          \
          else          TOUT[m2 * 4 + r4] = fmaf(q, sum, TOUT[m2 * 4 + r4]);  \
        }                                                                     \
      }                                                                       \
    }                                                                         \
  }

__global__ __launch_bounds__(64, 1) void liepe_mfma(
    const float* __restrict__ x,
    const float* __restrict__ r_grid,
    const _Float16* __restrict__ wsA,
    float* __restrict__ out,
    int n_tokens)
{
    const int lane = threadIdx.x;      // one wave per block
    const int c = lane & 15;           // token column
    const int g = lane >> 4;           // row sub-block / k-group

    int tok = blockIdx.x * 16 + c;
    if (tok >= n_tokens) tok = n_tokens - 1;

    // Resident A-fragments: 24 hi + 24 lo (192 VGPRs), f = gen*8 + m2*2 + kt.
    half8 Ah[24], Al[24];
    #pragma unroll
    for (int f = 0; f < 24; ++f) {
        Ah[f] = *(const half8*)(wsA + f * 512 + lane * 8);
        Al[f] = *(const half8*)(wsA + 12288 + f * 512 + lane * 8);
    }

    // x in D-layout: xv[4*m2+r4] = x[tok][16*m2 + 4*g + r4].
    float xv[16];
    #pragma unroll
    for (int m2 = 0; m2 < 4; ++m2) {
        float4 v = *(const float4*)(x + tok * 64 + 16 * m2 + 4 * g);
        xv[4 * m2 + 0] = v.x; xv[4 * m2 + 1] = v.y;
        xv[4 * m2 + 2] = v.z; xv[4 * m2 + 3] = v.w;
    }

    const float r0 = r_grid[tok * 3 + 0];
    const float r1 = r_grid[tok * 3 + 1];
    const float r2 = r_grid[tok * 3 + 2];
    const float sig2 = 0.5f * (r0 * r0 + r1 * r1 + r2 * r2);
    const float rho  = fmaf(17.3f, __builtin_sqrtf(sig2), 2.0f);
    const float inv_rho = 1.0f / rho;
    const int   M  = (int)rho + 14;     // >= ceil(rho)+13 -> tail ~1e-4
    const int   ms = M + 10;
    const float q0 = r0 * inv_rho, q1 = r1 * inv_rho, q2 = r2 * inv_rho;

    // wave max degree over its 16 tokens
    int maxM = M;
    #pragma unroll
    for (int off = 1; off < 64; off <<= 1)
        maxM = max(maxM, __shfl_xor(maxM, off));

    float jp = 0.f, jc = 0.f, N = 0.f;
    float b1[16], b2[16];
    #pragma unroll
    for (int i = 0; i < 16; ++i) { b1[i] = 0.f; b2[i] = 0.f; }

    // ---- descent: Miller only (all b's exactly 0) ----
    #pragma unroll 1
    for (int m = maxM + 10; m > maxM; --m) {
        bool sd = (m == ms);
        jc = sd ? 1e-12f : jc;
        jp = sd ? 0.f : jp;
        N  = sd ? (((m & 1) == 0) ? 2e-12f : 0.f) : N;
        float s = (jc > 1.0f) ? __builtin_amdgcn_rcpf(jc) : 1.0f;
        jc *= s; jp *= s; N *= s;
        float jm = fmaf((2.f * (float)m) * inv_rho, jc, -jp);
        jp = jc; jc = jm;
        int mm = m - 1;
        if ((mm & 1) == 0) N += (mm > 0) ? (jm + jm) : jm;
    }

    half8 Bh[2], Bl[2];

    // ---- main fused Miller+Clenshaw loop: fully register-resident ----
    #pragma unroll 1
    for (int m = maxM; m >= 1; --m) {
        bool sd = (m == ms);
        jc = sd ? 1e-12f : jc;
        jp = sd ? 0.f : jp;
        N  = sd ? (((m & 1) == 0) ? 2e-12f : 0.f) : N;

        // scale-invariant renorm keeps jc ~ O(1), b in f16 range
        float s = (jc > 1.0f) ? __builtin_amdgcn_rcpf(jc) : 1.0f;
        jc *= s; jp *= s; N *= s;
        #pragma unroll
        for (int i = 0; i < 16; ++i) { b1[i] *= s; b2[i] *= s; }

        PACK_B();

        float t[16];
        GEMM_COMBINE(t);

        float cf = (m <= M) ? (jc + jc) : 0.f;
        #pragma unroll
        for (int i = 0; i < 16; ++i) {
            float bn = fmaf(cf, xv[i], t[i] + b2[i]);
            b2[i] = b1[i];
            b1[i] = bn;
        }

        float jm = fmaf((2.f * (float)m) * inv_rho, jc, -jp);
        jp = jc; jc = jm;
        int mm = m - 1;
        if ((mm & 1) == 0) N += (mm > 0) ? (jm + jm) : jm;
    }

    // ---- final: b0 = J0*x + (2A/rho)b1 + b2;  y = (b0 - 0.5*(2A/rho)b1)/N ----
    {
        PACK_B();
        float t[16];
        GEMM_COMBINE(t);
        #pragma unroll
        for (int m2 = 0; m2 < 4; ++m2) {
            float4 v;
            float y0 = fmaf(jc, xv[4 * m2 + 0], t[4 * m2 + 0] + b2[4 * m2 + 0]);
            float y1 = fmaf(jc, xv[4 * m2 + 1], t[4 * m2 + 1] + b2[4 * m2 + 1]);
            float y2 = fmaf(jc, xv[4 * m2 + 2], t[4 * m2 + 2] + b2[4 * m2 + 2]);
            float y3 = fmaf(jc, xv[4 * m2 + 3], t[4 * m2 + 3] + b2[4 * m2 + 3]);
            v.x = (y0 - 0.5f * t[4 * m2 + 0]) / N;
            v.y = (y1 - 0.5f * t[4 * m2 + 1]) / N;
            v.z = (y2 - 0.5f * t[4 * m2 + 2]) / N;
            v.w = (y3 - 0.5f * t[4 * m2 + 3]) / N;
            *(float4*)(out + tok * 64 + 16 * m2 + 4 * g) = v;
        }
    }
}

extern "C" void kernel_launch(void* const* d_in, const int* in_sizes, int n_in,
                              void* d_out, int out_size, void* d_ws, size_t ws_size,
                              hipStream_t stream) {
    const float* x = (const float*)d_in[0];
    const float* r = (const float*)d_in[1];
    const float* L = (const float*)d_in[2];
    // d_in[3] = P_sp: identity (allow_mixing=False) -> R_eff = R_r.
    float* out = (float*)d_out;
    _Float16* wsA = (_Float16*)d_ws;   // 48KB: 24 hi + 24 lo fragments

    int n_tokens = in_sizes[0] / 64;   // B*S = 8192

    liepe_prep<<<6, 256, 0, stream>>>(L, wsA);

    int nwg = (n_tokens + 15) / 16;
    liepe_mfma<<<nwg, 64, 0, stream>>>(x, r, wsA, out, n_tokens);
}

// Round 11
// 33.577 us; speedup vs baseline: 1.5589x; 1.5589x over previous
//
#include <hip/hip_runtime.h>

// ExplicitLiePE via MFMA: y[b,s] = expm(A) @ x[b,s], A = sum_k r_k * 0.5*(L_k - L_k^T).
//
// Structure = round-6 (best verified: 32.1us bench / ~27us main):
// 16-token groups, 4 waves/block row-split (wave w owns D-rows [16w,16w+16)),
// dbuf LDS b-exchange, 1 barrier/step, 512 blocks -> 2048 waves = 2/SIMD.
// Rounds 7-10 closed the alternatives empirically:
//   r7/r8: occupancy via column duplication -> 46us (2x work, phase-locked).
//   r9: dual-group fat blocks -> 1 wave/SIMD -> 37.7us.
//   r10: register-only single wave (k-slot sigma trick, zero LDS) -> 47.5us:
//        single-wave chains run ~1/3 of issue model; TLP >> exchange savings.
// Per-token-step: r6 = 43cy vs r5/r10 = 68-71cy. The machine wants 2 waves/SIMD.
//
// Round-11 trim: renormalization made CONDITIONAL. jc is O(1) in the
// oscillatory region (m < rho); the unconditional 11-value rescale multiplies
// by 1.0 most steps. `if (__any(jc > 2.0f))` skips it (wave-uniform: jc chains
// are bit-identical in all 4 waves). Exactness: the result is scale-invariant
// (final /N), so renorming less often is mathematically identical -- only
// rounding points move. Bound: growth/step <= 2*maxM/rho_min ~ 37x -> jc <= ~74
// before retrigger; b <= ~4e4 < f16 max 65504.
//
// Math (unchanged): G_k = (L_k - L_k^T).B, t[:,c] = sum_k (r_k[c]/rho_c) G_k[:,c]
// via v_mfma_f32_16x16x32_f16, f16 hi/lo split of both L' and b
// (Lhi.bhi + Lhi.blo + Llo.bhi; dropped term ~2^-24). Seed at m==ms, coeff
// gated by m<=M.
//
// Layouts:
//  - C/D: reg r of lane l = D[16*w + (l>>4)*4 + r][l&15] (HW-verified m89/m91).
//  - A/B k-slot bijection k = 8*(l>>4)+j within each K=32 tile.
//  - staging: stage[buf][hi/lo][token c][dword]; token stride 36 dwords.

typedef _Float16 half8 __attribute__((ext_vector_type(8)));
typedef __fp16 fp16x2 __attribute__((ext_vector_type(2)));
typedef float float4t __attribute__((ext_vector_type(4)));

union H2U { fp16x2 h; unsigned u; };

__device__ __forceinline__ unsigned pkrtz2(float a, float b) {
    H2U v; v.h = __builtin_amdgcn_cvt_pkrtz(a, b); return v.u;
}
__device__ __forceinline__ float h2lo(unsigned u) { H2U v; v.u = u; return (float)v.h[0]; }
__device__ __forceinline__ float h2hi(unsigned u) { H2U v; v.u = u; return (float)v.h[1]; }

// ---------------- prepass: skew-symmetrize + f16 hi/lo split into fragments ----
// ws layout (f16): hi at [f*512 + l*8 + j], lo at +12288, f = (gen*4+m2)*2+kt.
// Fragment element (l, j) of tile (gen, m2, kt) = L'[16m2 + (l&15)][32kt + 8*(l>>4) + j].
__global__ void liepe_prep(const float* __restrict__ L, _Float16* __restrict__ wsA)
{
    int t = blockIdx.x * 256 + threadIdx.x;
    if (t >= 1536) return;
    int l   = t & 63;
    int f   = t >> 6;
    int kt  = f & 1;
    int m   = (f >> 1) & 3;
    int gen = f >> 3;
    int i   = 16 * m + (l & 15);
    int kk0 = 32 * kt + 8 * (l >> 4);
    const float* Lg = L + gen * 4096;
    half8 hi, lo;
    #pragma unroll
    for (int j = 0; j < 8; ++j) {
        int kk = kk0 + j;
        float d = Lg[i * 64 + kk] - Lg[kk * 64 + i];
        _Float16 h = (_Float16)d;
        hi[j] = h;
        lo[j] = (_Float16)(d - (float)h);
    }
    *(half8*)(wsA + f * 512 + l * 8) = hi;
    *(half8*)(wsA + 12288 + f * 512 + l * 8) = lo;
}

// ---------------- main kernel: 4 waves per block, 16 tokens per block --------

#define PSTR 36   // token stride in dwords (b128-aligned reads)

// stage own b1 slice (hi/lo f16), sync, load full-K B fragments, flip buffer.
#define STAGE_AND_LOAD_B()                                                       \
  {                                                                              \
    unsigned h0 = pkrtz2(b1[0], b1[1]);                                          \
    unsigned h1 = pkrtz2(b1[2], b1[3]);                                          \
    unsigned l0 = pkrtz2(b1[0] - h2lo(h0), b1[1] - h2hi(h0));                    \
    unsigned l1 = pkrtz2(b1[2] - h2lo(h1), b1[3] - h2hi(h1));                    \
    const int di = 8 * w + 2 * g;                                                \
    *(uint2*)&stage[buf][0][c][di] = make_uint2(h0, h1);                         \
    *(uint2*)&stage[buf][1][c][di] = make_uint2(l0, l1);                         \
    __syncthreads();                                                             \
    _Pragma("unroll")                                                            \
    for (int kt = 0; kt < 2; ++kt) {                                             \
      Bh[kt] = *(const half8*)&stage[buf][0][c][16 * kt + 4 * g];                \
      Bl[kt] = *(const half8*)&stage[buf][1][c][16 * kt + 4 * g];                \
    }                                                                            \
    buf ^= 1;                                                                    \
  }

// 18 MFMAs for this wave's 16-row tile; kt-split accumulators (6 short chains).
#define GEMM_COMBINE(TOUT)                                                       \
  {                                                                              \
    _Pragma("unroll")                                                            \
    for (int gen = 0; gen < 3; ++gen) {                                          \
      float q = (gen == 0) ? q0 : ((gen == 1) ? q1 : q2);                        \
      float4t ac0 = {0.f, 0.f, 0.f, 0.f};                                        \
      float4t ac1 = {0.f, 0.f, 0.f, 0.f};                                        \
      ac0 = __builtin_amdgcn_mfma_f32_16x16x32_f16(Ah[gen*2+0], Bh[0], ac0, 0, 0, 0); \
      ac1 = __builtin_amdgcn_mfma_f32_16x16x32_f16(Ah[gen*2+1], Bh[1], ac1, 0, 0, 0); \
      ac0 = __builtin_amdgcn_mfma_f32_16x16x32_f16(Ah[gen*2+0], Bl[0], ac0, 0, 0, 0); \
      ac1 = __builtin_amdgcn_mfma_f32_16x16x32_f16(Ah[gen*2+1], Bl[1], ac1, 0, 0, 0); \
      ac0 = __builtin_amdgcn_mfma_f32_16x16x32_f16(Al[gen*2+0], Bh[0], ac0, 0, 0, 0); \
      ac1 = __builtin_amdgcn_mfma_f32_16x16x32_f16(Al[gen*2+1], Bh[1], ac1, 0, 0, 0); \
      _Pragma("unroll")                                                          \
      for (int r4 = 0; r4 < 4; ++r4) {                                           \
        float sum = ac0[r4] + ac1[r4];                                           \
        if (gen == 0) TOUT[r4] = q * sum;                                        \
        else          TOUT[r4] = fmaf(q, sum, TOUT[r4]);                         \
      }                                                                          \
    }                                                                            \
  }

__global__ __launch_bounds__(256) void liepe_mfma(
    const float* __restrict__ x,
    const float* __restrict__ r_grid,
    const _Float16* __restrict__ wsA,
    float* __restrict__ out,
    int n_tokens)
{
    __shared__ __align__(16) unsigned stage[2][2][16][PSTR];  // 18KB

    const int lane = threadIdx.x & 63;
    const int w    = threadIdx.x >> 6;   // row-slice / m2 tile, 0..3
    const int c    = lane & 15;          // token column
    const int g    = lane >> 4;          // k-group / row sub-block

    int tok = blockIdx.x * 16 + c;
    if (tok >= n_tokens) tok = n_tokens - 1;

    // A-fragments for this wave's row slice (m2 = w): 6 hi + 6 lo (48 VGPRs).
    half8 Ah[6], Al[6];
    #pragma unroll
    for (int gen = 0; gen < 3; ++gen) {
        #pragma unroll
        for (int kt = 0; kt < 2; ++kt) {
            const int f = (gen * 4 + w) * 2 + kt;
            Ah[gen * 2 + kt] = *(const half8*)(wsA + f * 512 + lane * 8);
            Al[gen * 2 + kt] = *(const half8*)(wsA + 12288 + f * 512 + lane * 8);
        }
    }

    // x slice in D-layout: xv[r4] = x[tok][16w + 4g + r4].
    float xv[4];
    {
        float4 v = *(const float4*)(x + tok * 64 + 16 * w + 4 * g);
        xv[0] = v.x; xv[1] = v.y; xv[2] = v.z; xv[3] = v.w;
    }

    // Per-token scalars — computed redundantly + identically in all 4 waves.
    const float r0 = r_grid[tok * 3 + 0];
    const float r1 = r_grid[tok * 3 + 1];
    const float r2 = r_grid[tok * 3 + 2];
    const float sig2 = 0.5f * (r0 * r0 + r1 * r1 + r2 * r2);
    const float rho  = fmaf(17.3f, __builtin_sqrtf(sig2), 2.0f);
    const float inv_rho = 1.0f / rho;
    const int   M  = (int)rho + 14;     // >= ceil(rho)+13 -> tail ~1e-4
    const int   ms = M + 10;
    const float q0 = r0 * inv_rho, q1 = r1 * inv_rho, q2 = r2 * inv_rho;

    // block max degree: wave-reduce suffices (every wave holds all 16 tokens).
    int maxM = M;
    #pragma unroll
    for (int off = 1; off < 64; off <<= 1)
        maxM = max(maxM, __shfl_xor(maxM, off));

    float jp = 0.f, jc = 0.f, N = 0.f;
    float b1[4] = {0.f, 0.f, 0.f, 0.f};
    float b2[4] = {0.f, 0.f, 0.f, 0.f};

    // ---- descent: Miller only (all b's exactly 0, no barriers needed) ----
    #pragma unroll 1
    for (int m = maxM + 10; m > maxM; --m) {
        bool sd = (m == ms);
        jc = sd ? 1e-12f : jc;
        jp = sd ? 0.f : jp;
        N  = sd ? (((m & 1) == 0) ? 2e-12f : 0.f) : N;
        float s = (jc > 1.0f) ? __builtin_amdgcn_rcpf(jc) : 1.0f;
        jc *= s; jp *= s; N *= s;
        float jm = fmaf((2.f * (float)m) * inv_rho, jc, -jp);
        jp = jc; jc = jm;
        int mm = m - 1;
        if ((mm & 1) == 0) N += (mm > 0) ? (jm + jm) : jm;
    }

    half8 Bh[2], Bl[2];
    int buf = 0;

    // ---- main fused Miller+Clenshaw loop (1 barrier per step, dbuf) ----
    #pragma unroll 1
    for (int m = maxM; m >= 1; --m) {
        bool sd = (m == ms);
        jc = sd ? 1e-12f : jc;
        jp = sd ? 0.f : jp;
        N  = sd ? (((m & 1) == 0) ? 2e-12f : 0.f) : N;

        // CONDITIONAL scale-invariant renorm (round-11): wave-uniform branch
        // (jc chain identical in all 4 waves); skipped when all lanes' jc
        // small. Result is exactly scale-invariant -> math unchanged, only
        // rounding points move.
        if (__any(jc > 2.0f)) {
            float s = (jc > 1.0f) ? __builtin_amdgcn_rcpf(jc) : 1.0f;
            jc *= s; jp *= s; N *= s;
            #pragma unroll
            for (int i = 0; i < 4; ++i) { b1[i] *= s; b2[i] *= s; }
        }

        STAGE_AND_LOAD_B();

        float t[4];
        GEMM_COMBINE(t);

        float cf = (m <= M) ? (jc + jc) : 0.f;
        #pragma unroll
        for (int i = 0; i < 4; ++i) {
            float bn = fmaf(cf, xv[i], t[i] + b2[i]);
            b2[i] = b1[i];
            b1[i] = bn;
        }

        float jm = fmaf((2.f * (float)m) * inv_rho, jc, -jp);
        jp = jc; jc = jm;
        int mm = m - 1;
        if ((mm & 1) == 0) N += (mm > 0) ? (jm + jm) : jm;
    }

    // ---- final: b0 = J0*x + (2A/rho)b1 + b2;  y = (b0 - 0.5*(2A/rho)b1)/N ----
    {
        STAGE_AND_LOAD_B();
        float t[4];
        GEMM_COMBINE(t);
        float4 v;
        float y0 = fmaf(jc, xv[0], t[0] + b2[0]);
        float y1 = fmaf(jc, xv[1], t[1] + b2[1]);
        float y2 = fmaf(jc, xv[2], t[2] + b2[2]);
        float y3 = fmaf(jc, xv[3], t[3] + b2[3]);
        v.x = (y0 - 0.5f * t[0]) / N;
        v.y = (y1 - 0.5f * t[1]) / N;
        v.z = (y2 - 0.5f * t[2]) / N;
        v.w = (y3 - 0.5f * t[3]) / N;
        *(float4*)(out + tok * 64 + 16 * w + 4 * g) = v;
    }
}

extern "C" void kernel_launch(void* const* d_in, const int* in_sizes, int n_in,
                              void* d_out, int out_size, void* d_ws, size_t ws_size,
                              hipStream_t stream) {
    const float* x = (const float*)d_in[0];
    const float* r = (const float*)d_in[1];
    const float* L = (const float*)d_in[2];
    // d_in[3] = P_sp: identity (allow_mixing=False) -> R_eff = R_r.
    float* out = (float*)d_out;
    _Float16* wsA = (_Float16*)d_ws;   // 48KB: 24 hi + 24 lo fragments

    int n_tokens = in_sizes[0] / 64;   // B*S = 8192

    liepe_prep<<<6, 256, 0, stream>>>(L, wsA);

    int nwg = (n_tokens + 15) / 16;
    liepe_mfma<<<nwg, 256, 0, stream>>>(x, r, wsA, out, n_tokens);
}